// Round 3
// baseline (55.142 us; speedup 1.0000x reference)
//
#include <hip/hip_runtime.h>

#define BB 32
#define NTT 1024
#define SS 4096
#define D4 128   // D/4 = 512/4
#define RPW 8    // rows per wave

typedef float f32x4 __attribute__((ext_vector_type(4)));

// One wave = 8 consecutive output rows (same b). 64 lanes x 2 float4 per row.
// L (valid text length) found per-wave via 2-round probe+ballot over the
// contiguous non-negative prefix of text[b]; amortized over 8 rows.
__global__ void __launch_bounds__(256) fused_upsample_kernel(
        const int* __restrict__ text,
        const int* __restrict__ seq_len,
        const f32x4* __restrict__ W4,     // [(VOCAB+1) * D4]
        f32x4* __restrict__ out4) {
    int wid  = (blockIdx.x << 2) + (threadIdx.x >> 6);  // wave id
    int lane = threadIdx.x & 63;
    int row0 = wid << 3;               // first of 8 consecutive rows
    int t0   = row0 & (SS - 1);
    int b    = row0 >> 12;

    const int* trow = text + b * NTT;

    // ---- round 1: probe every 16th position (covers 0..1008) ----
    int v1 = trow[lane << 4];
    unsigned long long m1 = __ballot(v1 < 0);
    int lo;
    if (m1 == 0ull) {
        lo = NTT - 16;
    } else {
        int p = __builtin_ctzll(m1);
        lo = (p == 0) ? 0 : ((p - 1) << 4);
    }
    // ---- round 2: probe lo..lo+63 (virtual -1 beyond NT) ----
    int k2 = lo + lane;
    int v2 = (k2 < NTT) ? trow[k2] : -1;
    unsigned long long m2 = __ballot(v2 < 0);
    int L = lo + __builtin_ctzll(m2);

    int A = seq_len[b];

    int base = 1, rr = 0, split = 0;
    if (L > 0) {
        base  = (int)((unsigned)A / (unsigned)L);
        rr    = A - base * L;
        split = (L - rr) * base;
    }

    // phase 1: all 8 source indices (wave-uniform math)
    int jj[RPW];
#pragma unroll
    for (int i = 0; i < RPW; ++i) {
        int t = t0 + i;
        int j;
        if (t < split) {
            j = (int)((unsigned)t / (unsigned)base);
        } else {
            j = (L - rr) + (int)((unsigned)(t - split) / (unsigned)(base + 1));
        }
        if (j > L - 1) j = L - 1;
        if (j < 0) j = 0;
        jj[i] = j;
    }

    // phase 2: all 8 token loads in flight (wave-uniform broadcast, L1/L2-hot)
    int tok[RPW];
#pragma unroll
    for (int i = 0; i < RPW; ++i) tok[i] = trow[jj[i]] + 1;

    // phase 3: gather + nontemporal store per row
    f32x4* orow = out4 + (long)row0 * D4;
#pragma unroll
    for (int i = 0; i < RPW; ++i) {
        f32x4 va = (f32x4)(0.0f);
        f32x4 vb = (f32x4)(0.0f);
        int t = t0 + i;
        if (t < A && L > 0) {
            const f32x4* wr = W4 + (long)tok[i] * D4;
            va = wr[lane];
            vb = wr[lane + 64];
        }
        __builtin_nontemporal_store(va, &orow[i * D4 + lane]);
        __builtin_nontemporal_store(vb, &orow[i * D4 + lane + 64]);
    }
}

extern "C" void kernel_launch(void* const* d_in, const int* in_sizes, int n_in,
                              void* d_out, int out_size, void* d_ws, size_t ws_size,
                              hipStream_t stream) {
    const int* text    = (const int*)d_in[0];
    const int* seq_len = (const int*)d_in[1];
    const f32x4* W4    = (const f32x4*)d_in[2];
    f32x4* out4        = (f32x4*)d_out;

    // one wave per 8 rows: B*S/8 waves = B*S/32 blocks of 256
    int nblocks = BB * SS / (4 * RPW);    // 4096
    fused_upsample_kernel<<<nblocks, 256, 0, stream>>>(text, seq_len, W4, out4);
}

// Round 4
// 52.566 us; speedup vs baseline: 1.0490x; 1.0490x over previous
//
#include <hip/hip_runtime.h>

#define BB 32
#define NTT 1024
#define SS 4096
#define D4 128   // D/4 = 512/4

typedef float f32x4 __attribute__((ext_vector_type(4)));

// One wave = one output row [D=512] = 64 lanes x 2 float4.
// L found in ONE memory round-trip: each lane loads 16 ints (4x int4) of the
// text row (64 lanes x 16 = 1024 = NT); contiguous-prefix => L = sum of
// popcounts of per-component ballots.
__global__ void __launch_bounds__(256) fused_upsample_kernel(
        const int* __restrict__ text,
        const int* __restrict__ seq_len,
        const f32x4* __restrict__ W4,     // [(VOCAB+1) * D4]
        f32x4* __restrict__ out4) {
    int wid  = (blockIdx.x << 2) + (threadIdx.x >> 6);  // global wave id = row id
    int lane = threadIdx.x & 63;
    int t = wid & (SS - 1);
    int b = wid >> 12;

    const int*  trow  = text + b * NTT;
    const int4* trow4 = (const int4*)trow;

    int A = seq_len[b];                   // independent, issues early

    // ---- single-round probe: 4 independent int4 loads (lane's 16 ints) ----
    int base4 = lane << 2;                // int4 index: lane*4
    int4 p0 = trow4[base4 + 0];
    int4 p1 = trow4[base4 + 1];
    int4 p2 = trow4[base4 + 2];
    int4 p3 = trow4[base4 + 3];

    int L = 0;
    L += __popcll(__ballot(p0.x >= 0));
    L += __popcll(__ballot(p0.y >= 0));
    L += __popcll(__ballot(p0.z >= 0));
    L += __popcll(__ballot(p0.w >= 0));
    L += __popcll(__ballot(p1.x >= 0));
    L += __popcll(__ballot(p1.y >= 0));
    L += __popcll(__ballot(p1.z >= 0));
    L += __popcll(__ballot(p1.w >= 0));
    L += __popcll(__ballot(p2.x >= 0));
    L += __popcll(__ballot(p2.y >= 0));
    L += __popcll(__ballot(p2.z >= 0));
    L += __popcll(__ballot(p2.w >= 0));
    L += __popcll(__ballot(p3.x >= 0));
    L += __popcll(__ballot(p3.y >= 0));
    L += __popcll(__ballot(p3.z >= 0));
    L += __popcll(__ballot(p3.w >= 0));

    f32x4 va = (f32x4)(0.0f);
    f32x4 vb = (f32x4)(0.0f);
    if (t < A && L > 0) {
        // wave-uniform length-regulator arithmetic
        int base  = (int)((unsigned)A / (unsigned)L);      // >= 2 here
        int rr    = A - base * L;
        int split = (L - rr) * base;
        int j;
        if (t < split) {
            j = (int)((unsigned)t / (unsigned)base);
        } else {
            j = (L - rr) + (int)((unsigned)(t - split) / (unsigned)(base + 1));
        }
        if (j > L - 1) j = L - 1;         // safety clamp (math guarantees j < L)
        int tok = trow[j] + 1;            // wave-uniform broadcast, L1-hot
        const f32x4* wr = W4 + (long)tok * D4;
        va = wr[lane];                    // 1 KB coalesced
        vb = wr[lane + 64];               // 1 KB coalesced, independent
    }
    f32x4* orow = out4 + (long)wid * D4;
    __builtin_nontemporal_store(va, &orow[lane]);
    __builtin_nontemporal_store(vb, &orow[lane + 64]);
}

extern "C" void kernel_launch(void* const* d_in, const int* in_sizes, int n_in,
                              void* d_out, int out_size, void* d_ws, size_t ws_size,
                              hipStream_t stream) {
    const int* text    = (const int*)d_in[0];
    const int* seq_len = (const int*)d_in[1];
    const f32x4* W4    = (const f32x4*)d_in[2];
    f32x4* out4        = (f32x4*)d_out;

    int nblocks = BB * SS / 4;            // 32768 blocks, 1 wave per row
    fused_upsample_kernel<<<nblocks, 256, 0, stream>>>(text, seq_len, W4, out4);
}

// Round 5
// 46.653 us; speedup vs baseline: 1.1820x; 1.1267x over previous
//
#include <hip/hip_runtime.h>

#define BB 32
#define NTT 1024
#define SS 4096
#define D4 128   // D/4 = 512/4

typedef float f32x4 __attribute__((ext_vector_type(4)));

// One wave = one output row [D=512] = 64 lanes x 2 float4.
// Round-2 proven structure (2-round probe+ballot for L) + XCD-chunked block
// swizzle so consecutive rows (sharing W_embed rows) stay on one XCD's L2.
__global__ void __launch_bounds__(256) fused_upsample_kernel(
        const int* __restrict__ text,
        const int* __restrict__ seq_len,
        const f32x4* __restrict__ W4,     // [(VOCAB+1) * D4]
        f32x4* __restrict__ out4) {
    // bijective chunked XCD swizzle: nwg=32768 divisible by 8
    int bid  = (int)((blockIdx.x & 7) * 4096u + (blockIdx.x >> 3));
    int wid  = (bid << 2) + (threadIdx.x >> 6);         // row id
    int lane = threadIdx.x & 63;
    int t = wid & (SS - 1);
    int b = wid >> 12;

    const int* trow = text + b * NTT;

    int A = seq_len[b];                   // independent, issues early

    // ---- round 1: probe every 16th position (covers 0..1008) ----
    int v1 = trow[lane << 4];
    unsigned long long m1 = __ballot(v1 < 0);
    int lo;
    if (m1 == 0ull) {
        lo = NTT - 16;                    // first negative (if any) in (1008, 1024)
    } else {
        int p = __builtin_ctzll(m1);
        lo = (p == 0) ? 0 : ((p - 1) << 4);
    }
    // ---- round 2: probe lo..lo+63 (virtual -1 beyond NT) ----
    int k2 = lo + lane;
    int v2 = (k2 < NTT) ? trow[k2] : -1;
    unsigned long long m2 = __ballot(v2 < 0);
    int L = lo + __builtin_ctzll(m2);     // m2 != 0 guaranteed by virtual pad

    f32x4 va = (f32x4)(0.0f);
    f32x4 vb = (f32x4)(0.0f);
    if (t < A && L > 0) {
        // wave-uniform length-regulator arithmetic
        int base  = (int)((unsigned)A / (unsigned)L);      // >= 2 here
        int rr    = A - base * L;
        int split = (L - rr) * base;
        int j;
        if (t < split) {
            j = (int)((unsigned)t / (unsigned)base);
        } else {
            j = (L - rr) + (int)((unsigned)(t - split) / (unsigned)(base + 1));
        }
        if (j > L - 1) j = L - 1;         // safety clamp (math guarantees j < L)
        int tok = trow[j] + 1;            // wave-uniform broadcast, L2-hot
        const f32x4* wr = W4 + (long)tok * D4;
        va = wr[lane];                    // 1 KB coalesced
        vb = wr[lane + 64];               // 1 KB coalesced, independent
    }
    f32x4* orow = out4 + (long)wid * D4;
    __builtin_nontemporal_store(va, &orow[lane]);
    __builtin_nontemporal_store(vb, &orow[lane + 64]);
}

extern "C" void kernel_launch(void* const* d_in, const int* in_sizes, int n_in,
                              void* d_out, int out_size, void* d_ws, size_t ws_size,
                              hipStream_t stream) {
    const int* text    = (const int*)d_in[0];
    const int* seq_len = (const int*)d_in[1];
    const f32x4* W4    = (const f32x4*)d_in[2];
    f32x4* out4        = (f32x4*)d_out;

    int nblocks = BB * SS / 4;            // 32768 blocks, 1 wave per row
    fused_upsample_kernel<<<nblocks, 256, 0, stream>>>(text, seq_len, W4, out4);
}

// Round 6
// 45.732 us; speedup vs baseline: 1.2058x; 1.0201x over previous
//
#include <hip/hip_runtime.h>

#define BB 32
#define NTT 1024
#define SS 4096
#define D4 128   // D/4 = 512/4

typedef float f32x4 __attribute__((ext_vector_type(4)));

// One wave = one output row [D=512] = 64 lanes x 2 float4.
// L (valid text length) found per-wave via 2-round probe+ballot over the
// contiguous non-negative prefix of text[b].
// Best-proven structure (round 2, 45.9 us). Tested and rejected:
//   - RPW=8 row batching (55.1 us: serial chains per wave)
//   - single-round full-row probe (52.6 us: 16 serial ballots cost > 1 RT)
//   - XCD-chunked swizzle (46.7 us: reads are L3-absorbed, no L2 win)
__global__ void __launch_bounds__(256) fused_upsample_kernel(
        const int* __restrict__ text,
        const int* __restrict__ seq_len,
        const f32x4* __restrict__ W4,     // [(VOCAB+1) * D4]
        f32x4* __restrict__ out4) {
    int wid  = (blockIdx.x << 2) + (threadIdx.x >> 6);  // global wave id = row id
    int lane = threadIdx.x & 63;
    int t = wid & (SS - 1);
    int b = wid >> 12;

    const int* trow = text + b * NTT;

    // ---- round 1: probe every 16th position (covers 0..1008) ----
    int v1 = trow[lane << 4];
    unsigned long long m1 = __ballot(v1 < 0);
    int lo;
    if (m1 == 0ull) {
        lo = NTT - 16;                    // first negative (if any) in (1008, 1024)
    } else {
        int p = __builtin_ctzll(m1);
        lo = (p == 0) ? 0 : ((p - 1) << 4);
    }
    // ---- round 2: probe lo..lo+63 (virtual -1 beyond NT) ----
    int k2 = lo + lane;
    int v2 = (k2 < NTT) ? trow[k2] : -1;
    unsigned long long m2 = __ballot(v2 < 0);
    int L = lo + __builtin_ctzll(m2);     // m2 != 0 guaranteed by virtual pad

    int A = seq_len[b];

    f32x4 va = (f32x4)(0.0f);
    f32x4 vb = (f32x4)(0.0f);
    if (t < A && L > 0) {
        // wave-uniform length-regulator arithmetic
        int base  = (int)((unsigned)A / (unsigned)L);      // >= 2 here
        int rr    = A - base * L;
        int split = (L - rr) * base;
        int j;
        if (t < split) {
            j = (int)((unsigned)t / (unsigned)base);
        } else {
            j = (L - rr) + (int)((unsigned)(t - split) / (unsigned)(base + 1));
        }
        if (j > L - 1) j = L - 1;         // safety clamp (math guarantees j < L)
        int tok = trow[j] + 1;            // broadcast load, wave-uniform
        const f32x4* wr = W4 + (long)tok * D4;
        va = wr[lane];                    // 1 KB coalesced
        vb = wr[lane + 64];               // 1 KB coalesced, independent
    }
    f32x4* orow = out4 + (long)wid * D4;
    __builtin_nontemporal_store(va, &orow[lane]);
    __builtin_nontemporal_store(vb, &orow[lane + 64]);
}

extern "C" void kernel_launch(void* const* d_in, const int* in_sizes, int n_in,
                              void* d_out, int out_size, void* d_ws, size_t ws_size,
                              hipStream_t stream) {
    const int* text    = (const int*)d_in[0];
    const int* seq_len = (const int*)d_in[1];
    const f32x4* W4    = (const f32x4*)d_in[2];
    f32x4* out4        = (f32x4*)d_out;

    int nblocks = BB * SS / 4;            // 32768 blocks, 1 wave per row
    fused_upsample_kernel<<<nblocks, 256, 0, stream>>>(text, seq_len, W4, out4);
}